// Round 6
// baseline (553.407 us; speedup 1.0000x reference)
//
#include <hip/hip_runtime.h>
#include <stdint.h>

// ---- problem constants ----
constexpr int Hh = 512, Ww = 512;
constexpr int HW = Hh * Ww;
constexpr int C  = 32;
constexpr int B  = 2;
constexpr int NL = 50000;
constexpr int NR = 20000;
constexpr float EPS = 1e-5f;
constexpr float SCALE = 0.25f;        // 1/sqrt(16)

// block ranges for kernel 2
constexpr int GBL = (NL + NR + 255) / 256;   // grid scatter blocks
constexpr int LB  = (NL + 255) / 256;        // lidar ln blocks
constexpr int RB  = (NR + 255) / 256;        // radar ln blocks

// 3x3 INDEX_SHIFT order from reference
__device__ __constant__ int DX9[9] = {0,-1,1,0,-1,1,0,-1,1};
__device__ __constant__ int DY9[9] = {0,0,0,1,1,1,-1,-1,-1};

// ==================== kernel 2: grid scatter + LN/projection ====================
// bx < GBL: scatter pillar indices into grids + rdy cells.
// else: LN + 3 fused matvecs; each block computes its own combined mats in LDS.
__global__ void build_proj_k(const int* __restrict__ li_c, const int* __restrict__ ra_c,
                             const int* __restrict__ ra_dy,
                             int* __restrict__ li_grid, int* __restrict__ ra_grid,
                             uint8_t* __restrict__ rdy_grid,          // 0xFF = not dy, 0 = dy
                             const float* __restrict__ li_f, const float* __restrict__ ra_f,
                             const float* __restrict__ ln_li_w, const float* __restrict__ ln_li_b,
                             const float* __restrict__ ln_ra_w, const float* __restrict__ ln_ra_b,
                             const float* __restrict__ a1iw, const float* __restrict__ a1ib,
                             const float* __restrict__ a2iw, const float* __restrict__ a2ib,
                             const float* __restrict__ q1w, const float* __restrict__ q1b,
                             const float* __restrict__ k1w, const float* __restrict__ k1b,
                             const float* __restrict__ v1w, const float* __restrict__ v1b,
                             const float* __restrict__ q2w, const float* __restrict__ q2b,
                             const float* __restrict__ k2w, const float* __restrict__ k2b,
                             const float* __restrict__ v2w, const float* __restrict__ v2b,
                             float* __restrict__ qp1, float* __restrict__ kp1, float* __restrict__ vp1,
                             float* __restrict__ qp2, float* __restrict__ kp2, float* __restrict__ vp2) {
    int bx = blockIdx.x, b = blockIdx.y, t = threadIdx.x;
    if (bx < GBL) {
        int i = bx * 256 + t;
        if (i < NL) {
            int x = li_c[((size_t)b * NL + i) * 2 + 0];
            int y = li_c[((size_t)b * NL + i) * 2 + 1];
            li_grid[(size_t)b * HW + x * Ww + y] = i;
        } else if (i < NL + NR) {
            int j = i - NL;
            int x = ra_c[((size_t)b * NR + j) * 2 + 0];
            int y = ra_c[((size_t)b * NR + j) * 2 + 1];
            ra_grid[(size_t)b * HW + x * Ww + y] = j;
            if (ra_dy[(size_t)b * NR + j] != 0)
                rdy_grid[(size_t)b * HW + x * Ww + y] = 0;
        }
        return;
    }

    // ---- LN + projection path ----
    bool lidar = (bx - GBL < LB);
    int n = lidar ? NL : NR;
    int i = (lidar ? bx - GBL : bx - GBL - LB) * 256 + t;
    const float* feats = lidar ? li_f : ra_f;
    const float* lnw = lidar ? ln_li_w : ln_ra_w;
    const float* lnb = lidar ? ln_li_b : ln_ra_b;
    // lidar feeds q of branch1, k/v of branch2; radar feeds q of branch2, k/v of branch1
    const float* Asec[3] = { (lidar ? a1iw : a2iw) + 0 * C * C,
                             (lidar ? a2iw : a1iw) + 1 * C * C,
                             (lidar ? a2iw : a1iw) + 2 * C * C };
    const float* absec[3] = { (lidar ? a1ib : a2ib) + 0 * C,
                              (lidar ? a2ib : a1ib) + 1 * C,
                              (lidar ? a2ib : a1ib) + 2 * C };
    const float* Wsec[3] = { lidar ? q1w : q2w, lidar ? k2w : k1w, lidar ? v2w : v1w };
    const float* bsec[3] = { lidar ? q1b : q2b, lidar ? k2b : k1b, lidar ? v2b : v1b };
    float* outp[3] = { lidar ? qp1 : qp2, lidar ? kp2 : kp1, lidar ? vp2 : vp1 };

    __shared__ float sM[3][1024];
    __shared__ float sc[3][32];
    for (int p = t; p < 3072; p += 256) {
        int m = p >> 10, e = p & 1023, r = e >> 5, d = e & 31;
        float s = 0.f;
        #pragma unroll
        for (int c = 0; c < C; ++c) s += Asec[m][r * C + c] * Wsec[m][c * C + d];
        sM[m][e] = s;
    }
    if (t < 96) {
        int m = t >> 5, r = t & 31;
        float s = absec[m][r];
        #pragma unroll
        for (int c = 0; c < C; ++c) s += Asec[m][r * C + c] * bsec[m][c];
        sc[m][r] = s;
    }
    __syncthreads();
    if (i >= n) return;

    float x[C];
    const float4* f4 = (const float4*)(feats + ((size_t)b * n + i) * C);
    #pragma unroll
    for (int q = 0; q < 8; ++q) {
        float4 tv = f4[q];
        x[4*q] = tv.x; x[4*q+1] = tv.y; x[4*q+2] = tv.z; x[4*q+3] = tv.w;
    }
    float mu = 0.f;
    #pragma unroll
    for (int c = 0; c < C; ++c) mu += x[c];
    mu *= (1.0f / C);
    float var = 0.f;
    #pragma unroll
    for (int c = 0; c < C; ++c) { float d = x[c] - mu; var += d * d; }
    var *= (1.0f / C);
    float inv = 1.0f / sqrtf(var + EPS);
    #pragma unroll
    for (int c = 0; c < C; ++c) x[c] = (x[c] - mu) * inv * lnw[c] + lnb[c];

    #pragma unroll
    for (int m = 0; m < 3; ++m) {
        float4* o4 = (float4*)(outp[m] + ((size_t)b * n + i) * C);
        #pragma unroll
        for (int rq = 0; rq < 8; ++rq) {
            float4 tv;
            float* tp = &tv.x;
            #pragma unroll
            for (int rr = 0; rr < 4; ++rr) {
                int r = rq * 4 + rr;
                float s = sc[m][r];
                #pragma unroll
                for (int d = 0; d < C; ++d) s += sM[m][r * C + d] * x[d];
                tp[rr] = s;
            }
            o4[rq] = tv;
        }
    }
}

// ---- per-cell attention body (shared by both branches) ----
__device__ __forceinline__ void attn_cell(
        int x, int y, int nkv,
        const float* __restrict__ qrow,      // global, 32 floats
        const float* __restrict__ kmap, const float* __restrict__ vmap,
        const int* __restrict__ kv_grid,     // batch-offset applied by caller
        const float* sWo, const float* sbo, const float* spe,
        const float* skinv, const float* svinv,
        float* v) {
    int nidx[9];
    #pragma unroll
    for (int j = 0; j < 9; ++j) {
        int sx = x + DX9[j], sy = y + DY9[j];
        nidx[j] = (sx >= 0 && sx < Hh && sy >= 0 && sy < Ww) ? kv_grid[sx * Ww + sy] : -1;
    }
    float qp[C];
    const float4* qp4 = (const float4*)qrow;
    #pragma unroll
    for (int q = 0; q < 8; ++q) {
        float4 tv = qp4[q];
        qp[4*q] = tv.x; qp[4*q+1] = tv.y; qp[4*q+2] = tv.z; qp[4*q+3] = tv.w;
    }
    // scores (invalid slots use bias-only K — reference does NOT mask attention)
    float sc0[9], sc1[9];
    #pragma unroll
    for (int j = 0; j < 9; ++j) {
        int idx = nidx[j];
        const float4* kp4 = (idx >= 0) ? (const float4*)(kmap + (size_t)idx * C)
                                       : (const float4*)skinv;
        float s0 = 0.f, s1 = 0.f;
        #pragma unroll
        for (int q = 0; q < 4; ++q) {
            float4 tv = kp4[q];
            s0 += qp[4*q] * tv.x + qp[4*q+1] * tv.y + qp[4*q+2] * tv.z + qp[4*q+3] * tv.w;
        }
        #pragma unroll
        for (int q = 4; q < 8; ++q) {
            float4 tv = kp4[q];
            s1 += qp[4*q] * tv.x + qp[4*q+1] * tv.y + qp[4*q+2] * tv.z + qp[4*q+3] * tv.w;
        }
        sc0[j] = s0 * SCALE; sc1[j] = s1 * SCALE;
    }
    float m0 = sc0[0], m1 = sc1[0];
    #pragma unroll
    for (int j = 1; j < 9; ++j) { m0 = fmaxf(m0, sc0[j]); m1 = fmaxf(m1, sc1[j]); }
    float sum0 = 0.f, sum1 = 0.f;
    #pragma unroll
    for (int j = 0; j < 9; ++j) {
        sc0[j] = expf(sc0[j] - m0); sum0 += sc0[j];
        sc1[j] = expf(sc1[j] - m1); sum1 += sc1[j];
    }
    float r0 = 1.0f / sum0, r1 = 1.0f / sum1;

    float o[C];
    #pragma unroll
    for (int c = 0; c < C; ++c) o[c] = 0.f;
    #pragma unroll
    for (int j = 0; j < 9; ++j) {
        float a0 = sc0[j] * r0, a1 = sc1[j] * r1;
        int idx = nidx[j];
        if (idx >= 0) {
            const float4* vp4 = (const float4*)(vmap + (size_t)idx * C);
            #pragma unroll
            for (int q = 0; q < 8; ++q) {
                float4 tv = vp4[q];
                float a = (q < 4) ? a0 : a1;
                o[4*q]   += a * (tv.x + spe[j * 32 + 4*q]);
                o[4*q+1] += a * (tv.y + spe[j * 32 + 4*q+1]);
                o[4*q+2] += a * (tv.z + spe[j * 32 + 4*q+2]);
                o[4*q+3] += a * (tv.w + spe[j * 32 + 4*q+3]);
            }
        } else {
            #pragma unroll
            for (int d = 0; d < 16; ++d) {
                o[d]      += a0 * svinv[d];
                o[16 + d] += a1 * svinv[16 + d];
            }
        }
    }
    #pragma unroll
    for (int r = 0; r < C; ++r) {
        float s = sbo[r];
        #pragma unroll
        for (int c = 0; c < C; ++c) s += sWo[r * C + c] * o[c];
        v[r] = s;
    }
}

// ==================== kernel 3: thread-per-cell fused attn + densify ====================
__global__ void attn_canvas_k(const int* __restrict__ li_grid, const int* __restrict__ ra_grid,
                              const uint8_t* __restrict__ rdy_grid,
                              const float* __restrict__ qp1, const float* __restrict__ kp1,
                              const float* __restrict__ vp1, const float* __restrict__ qp2,
                              const float* __restrict__ kp2, const float* __restrict__ vp2,
                              const float* __restrict__ a1iw, const float* __restrict__ a1ib,
                              const float* __restrict__ a2iw, const float* __restrict__ a2ib,
                              const float* __restrict__ posw, const float* __restrict__ posb,
                              const float* __restrict__ a1ow, const float* __restrict__ a1ob,
                              const float* __restrict__ a2ow, const float* __restrict__ a2ob,
                              float* __restrict__ out_li, float* __restrict__ out_ra) {
    __shared__ alignas(16) float sWo1[1024], sWo2[1024];
    __shared__ alignas(16) float sbo1[32], sbo2[32];
    __shared__ alignas(16) float spe1[288], spe2[288];
    __shared__ alignas(16) float skinv1[32], svinv1[32], skinv2[32], svinv2[32];
    int t = threadIdx.x;
    for (int p = t; p < 1024; p += 256) { sWo1[p] = a1ow[p]; sWo2[p] = a2ow[p]; }
    if (t < 32) {
        sbo1[t] = a1ob[t]; sbo2[t] = a2ob[t];
        skinv1[t] = a1ib[32 + t]; svinv1[t] = a1ib[64 + t];
        skinv2[t] = a2ib[32 + t]; svinv2[t] = a2ib[64 + t];
    }
    for (int p = t; p < 576; p += 256) {              // projected pos-enc: A{1,2}v @ pe9[j]
        int br = p / 288; int e = p % 288; int j = e >> 5, r = e & 31;
        const float* Av = (br == 0 ? a1iw : a2iw) + 2 * C * C;
        float sx = (float)DX9[j], sy = (float)DY9[j];
        float s = 0.f;
        #pragma unroll
        for (int c = 0; c < C; ++c) {
            float pe = posw[c * 2 + 0] * sx + posw[c * 2 + 1] * sy + posb[c];
            s += Av[r * C + c] * pe;
        }
        (br == 0 ? spe1 : spe2)[e] = s;
    }
    __syncthreads();

    int b = blockIdx.y;
    int cell = blockIdx.x * 256 + t;
    int x = cell >> 9, y = cell & 511;
    size_t gidx = (size_t)b * HW + cell;
    size_t obase = (size_t)b * C * HW + cell;

    int li = li_grid[gidx];
    int ra = ra_grid[gidx];
    const uint8_t* rdy = rdy_grid + (size_t)b * HW;

    float v[C];
    // ---- branch 1: lidar query at this cell (dy-gated) ----
    bool do1 = false;
    if (li >= 0) {
        // 5x5 window with mod-513 wrap (reference semantics; coord 512 invalid)
        #pragma unroll
        for (int dx = -2; dx <= 2 && !do1; ++dx) {
            int cx = x + dx;
            cx = (cx < 0) ? cx + 513 : (cx >= 513 ? cx - 513 : cx);
            if (cx == 512) continue;
            #pragma unroll
            for (int dyy = -2; dyy <= 2; ++dyy) {
                int cy = y + dyy;
                cy = (cy < 0) ? cy + 513 : (cy >= 513 ? cy - 513 : cy);
                if (cy == 512) continue;
                if (rdy[cx * Ww + cy] == 0) { do1 = true; break; }
            }
        }
    }
    if (do1) {
        attn_cell(x, y, NR, qp1 + ((size_t)b * NL + li) * C,
                  kp1 + (size_t)b * NR * C, vp1 + (size_t)b * NR * C,
                  ra_grid + (size_t)b * HW, sWo1, sbo1, spe1, skinv1, svinv1, v);
    } else {
        #pragma unroll
        for (int c = 0; c < C; ++c) v[c] = 0.f;
    }
    #pragma unroll
    for (int c = 0; c < C; ++c) out_li[obase + (size_t)c * HW] = v[c];

    // ---- branch 2: radar query at this cell ----
    if (ra >= 0) {
        attn_cell(x, y, NL, qp2 + ((size_t)b * NR + ra) * C,
                  kp2 + (size_t)b * NL * C, vp2 + (size_t)b * NL * C,
                  li_grid + (size_t)b * HW, sWo2, sbo2, spe2, skinv2, svinv2, v);
    } else {
        #pragma unroll
        for (int c = 0; c < C; ++c) v[c] = 0.f;
    }
    #pragma unroll
    for (int c = 0; c < C; ++c) out_ra[obase + (size_t)c * HW] = v[c];
}

extern "C" void kernel_launch(void* const* d_in, const int* in_sizes, int n_in,
                              void* d_out, int out_size, void* d_ws, size_t ws_size,
                              hipStream_t stream) {
    const float*   li_f  = (const float*)d_in[0];
    const int*     li_c  = (const int*)d_in[1];
    const float*   ra_f  = (const float*)d_in[2];
    const int*     ra_c  = (const int*)d_in[3];
    const int*     ra_dy = (const int*)d_in[4];   // jnp bool staged as int32
    const float* ln_li_w = (const float*)d_in[5];
    const float* ln_li_b = (const float*)d_in[6];
    const float* ln_ra_w = (const float*)d_in[7];
    const float* ln_ra_b = (const float*)d_in[8];
    const float* q1w = (const float*)d_in[9],  *q1b = (const float*)d_in[10];
    const float* k1w = (const float*)d_in[11], *k1b = (const float*)d_in[12];
    const float* v1w = (const float*)d_in[13], *v1b = (const float*)d_in[14];
    const float* q2w = (const float*)d_in[15], *q2b = (const float*)d_in[16];
    const float* k2w = (const float*)d_in[17], *k2b = (const float*)d_in[18];
    const float* v2w = (const float*)d_in[19], *v2b = (const float*)d_in[20];
    const float* posw = (const float*)d_in[21], *posb = (const float*)d_in[22];
    const float* a1iw = (const float*)d_in[23], *a1ib = (const float*)d_in[24];
    const float* a1ow = (const float*)d_in[25], *a1ob = (const float*)d_in[26];
    const float* a2iw = (const float*)d_in[27], *a2ib = (const float*)d_in[28];
    const float* a2ow = (const float*)d_in[29], *a2ob = (const float*)d_in[30];

    // ---- workspace carve-up (256B aligned); grids+rdy contiguous for one memset ----
    char* ws = (char*)d_ws;
    size_t off = 0;
    auto carve = [&](size_t bytes) { void* p = ws + off; off += (bytes + 255) & ~(size_t)255; return p; };
    int*     li_grid  = (int*)carve((size_t)B * HW * 4);
    int*     ra_grid  = (int*)carve((size_t)B * HW * 4);
    uint8_t* rdy_grid = (uint8_t*)carve((size_t)B * HW);   // 0xFF = not dy, 0 = dy
    size_t   init_bytes = off;                             // everything above inits to 0xFF
    float*   qp1 = (float*)carve((size_t)B * NL * C * 4);
    float*   kp1 = (float*)carve((size_t)B * NR * C * 4);
    float*   vp1 = (float*)carve((size_t)B * NR * C * 4);
    float*   qp2 = (float*)carve((size_t)B * NR * C * 4);
    float*   kp2 = (float*)carve((size_t)B * NL * C * 4);
    float*   vp2 = (float*)carve((size_t)B * NL * C * 4);
    (void)ws_size; (void)n_in; (void)in_sizes; (void)out_size;

    float* out_li = (float*)d_out;
    float* out_ra = out_li + (size_t)B * C * HW;

    // 1) grids to -1, rdy_grid to 0xFF
    hipMemsetAsync(li_grid, 0xFF, init_bytes, stream);

    // 2) grid scatter + LN/projection (block-local constants, no ordering hazard)
    build_proj_k<<<dim3(GBL + LB + RB, B), dim3(256), 0, stream>>>(
        li_c, ra_c, ra_dy, li_grid, ra_grid, rdy_grid,
        li_f, ra_f, ln_li_w, ln_li_b, ln_ra_w, ln_ra_b,
        a1iw, a1ib, a2iw, a2ib,
        q1w, q1b, k1w, k1b, v1w, v1b, q2w, q2b, k2w, k2b, v2w, v2b,
        qp1, kp1, vp1, qp2, kp2, vp2);

    // 3) thread-per-cell fused attention + densification (coalesced canvas writes)
    attn_canvas_k<<<dim3(HW / 256, B), dim3(256), 0, stream>>>(
        li_grid, ra_grid, rdy_grid, qp1, kp1, vp1, qp2, kp2, vp2,
        a1iw, a1ib, a2iw, a2ib, posw, posb, a1ow, a1ob, a2ow, a2ob,
        out_li, out_ra);
}